// Round 9
// baseline (726.293 us; speedup 1.0000x reference)
//
#include <hip/hip_runtime.h>
#include <hip/hip_bf16.h>

#define BB 512      // batch
#define DD 2048     // input dim
#define KK 4096     // code dim
#define CC 512      // cause dim
#define LR 0.001f
#define GAMMA 0.1f

typedef __attribute__((ext_vector_type(8))) short short8;
typedef __attribute__((ext_vector_type(4))) float f32x4;
typedef __attribute__((ext_vector_type(16))) float f32x16;

__device__ __forceinline__ unsigned short f2bf(float f) {
  union { float f; unsigned u; } x; x.f = f;
  unsigned r = x.u + 0x7FFF + ((x.u >> 16) & 1);   // RNE
  return (unsigned short)(r >> 16);
}

__device__ __forceinline__ void g2l16(const void* g, void* l) {
  __builtin_amdgcn_global_load_lds(
      (const __attribute__((address_space(1))) void*)g,
      (__attribute__((address_space(3))) void*)l, 16, 0, 0);
}

__device__ __forceinline__ void store4bf(unsigned short* p, f32x4 v) {
  const unsigned lo = (unsigned)f2bf(v[0]) | ((unsigned)f2bf(v[1]) << 16);
  const unsigned hi = (unsigned)f2bf(v[2]) | ((unsigned)f2bf(v[3]) << 16);
  *(uint2*)p = uint2{lo, hi};
}

// ---------------------------------------------------------------------------
// 128x128-tile K-loop, BK=32, mfma_f32_32x32x16_bf16, 4 waves 2x2 (wave tile
// 64x64 = 2x2 of 32x32 frags, 8 MFMA/wave/iter = 262144 FLOP). LDS layout
// per tile: [BK/8=4][128][8] bf16 (k-blocked) -> every 32-lane frag read is a
// contiguous 512B block (conflict-free, NO swizzle); staging writes are the
// linear global_load_lds pattern with per-lane source row = lane.
// 3 buffer sets (48 KB total -> 3 blocks/CU), 2 tiles ahead, counted vmcnt
// (4 loads/wave/tile). Single barrier/iter: wave's tile-t ds_reads retire
// before its MFMAs issue (compiler lgkm waits) which precede barrier(t+1),
// so restaging buf (t+2)%3 after barrier(t) is race-free (R4-R8 proven).
// ---------------------------------------------------------------------------
__device__ __forceinline__ void mm2(
    const unsigned short* __restrict__ agl,  // A + (bm + lane)*Kd
    const unsigned short* __restrict__ bgl,  // Bm + (bn + lane)*Kd
    int Kd, int nt,
    unsigned short* As, unsigned short* Bs,  // [3][4096] elems each
    int w, int hw, int l31, int wr, int wc,
    f32x16 acc[2][2]) {
  // wave w stages k-block kb=w: rows 0-63 then 64-127, for A and B
  auto STG = [&](int ti, int buf) {
    const int k0 = ti * 32 + w * 8;
    unsigned short* Ab = As + buf * 4096 + w * 1024;
    unsigned short* Bb = Bs + buf * 4096 + w * 1024;
    g2l16(agl + k0, Ab);
    g2l16(agl + (size_t)64 * Kd + k0, Ab + 512);
    g2l16(bgl + k0, Bb);
    g2l16(bgl + (size_t)64 * Kd + k0, Bb + 512);
  };
  STG(0, 0);
  if (nt > 1) STG(1, 1);
  int cb = 0, sb = 2;
  for (int t = 0; t < nt; t++) {
    if (t + 1 < nt) asm volatile("s_waitcnt vmcnt(4)" ::: "memory");
    else            asm volatile("s_waitcnt vmcnt(0)" ::: "memory");
    __builtin_amdgcn_s_barrier();
    if (t + 2 < nt) STG(t + 2, sb);

    const unsigned short* Ab = As + cb * 4096;
    const unsigned short* Bb = Bs + cb * 4096;
#pragma unroll
    for (int ks = 0; ks < 2; ks++) {
      const int kb = ks * 2 + hw;          // k-block for this half-wave
      short8 af[2], bf2[2];
#pragma unroll
      for (int m = 0; m < 2; m++)
        af[m] = *(const short8*)(Ab + (kb * 128 + wr * 64 + m * 32 + l31) * 8);
#pragma unroll
      for (int n = 0; n < 2; n++)
        bf2[n] = *(const short8*)(Bb + (kb * 128 + wc * 64 + n * 32 + l31) * 8);
#pragma unroll
      for (int m = 0; m < 2; m++)
#pragma unroll
        for (int n = 0; n < 2; n++)
          acc[m][n] = __builtin_amdgcn_mfma_f32_32x32x16_bf16(af[m], bf2[n], acc[m][n], 0, 0, 0);
    }
    cb = (cb + 1 == 3) ? 0 : cb + 1;
    sb = (sb + 1 == 3) ? 0 : sb + 1;
  }
}

#define LANE_SETUP                                             \
  const int tid = threadIdx.x;                                 \
  const int w = tid >> 6, l = tid & 63;                        \
  const int wr = w >> 1, wc = w & 1;                           \
  const int hw = l >> 5, l31 = l & 31;

#define ACC_INIT(a)                                            \
  _Pragma("unroll") for (int m = 0; m < 2; m++)                \
  _Pragma("unroll") for (int n = 0; n < 2; n++)                \
  _Pragma("unroll") for (int q = 0; q < 16; q++)               \
      a[m][n][q] = 0.f;

// C/D 32x32 layout: col = lane&31, row = (q&3) + 8*(q>>2) + 4*(lane>>5)
#define ACC_STORE(dst, N)                                                   \
  _Pragma("unroll") for (int m = 0; m < 2; m++)                             \
  _Pragma("unroll") for (int n = 0; n < 2; n++)                             \
  _Pragma("unroll") for (int q = 0; q < 16; q++)                            \
      (dst)[(size_t)(bm + wr * 64 + m * 32 + (q & 3) + 8 * (q >> 2) + 4 * hw) * (N) \
            + bn + wc * 64 + n * 32 + l31] = acc[m][n][q];

// Launch A: j<512  -> gx partials (split-K=4, 16 iters): gxp[ks] = r@Wb^T
//           j>=512 -> z tiles (16 iters): z = ub@Vt^T
__global__ __launch_bounds__(256, 3)
void zgxp_k(const unsigned short* __restrict__ r,    // (BB,DD)
            const unsigned short* __restrict__ Wb,   // (KK,DD)
            const unsigned short* __restrict__ ub,   // (BB,CC)
            const unsigned short* __restrict__ Vt,   // (KK,CC)
            float* __restrict__ gxp,                 // 4 x (BB,KK)
            float* __restrict__ z) {                 // (BB,KK)
  __shared__ unsigned short As[3][4096];
  __shared__ unsigned short Bs[3][4096];
  LANE_SETUP
  const int j = blockIdx.x;
  f32x16 acc[2][2];
  ACC_INIT(acc)
  if (j < 512) {
    const int T = j >> 2, ks = j & 3;                // T in [0,128)
    const int bm = (T >> 5) * 128, bn = (T & 31) * 128;
    mm2(r  + (size_t)(bm + l) * DD + ks * 512,
        Wb + (size_t)(bn + l) * DD + ks * 512,
        DD, 16, &As[0][0], &Bs[0][0], w, hw, l31, wr, wc, acc);
    float* dst = gxp + (size_t)ks * BB * KK;
    ACC_STORE(dst, KK)
  } else {
    const int T = j - 512;                           // [0,128)
    const int bm = (T >> 5) * 128, bn = (T & 31) * 128;
    mm2(ub + (size_t)(bm + l) * CC,
        Vt + (size_t)(bn + l) * CC,
        CC, 16, &As[0][0], &Bs[0][0], w, hw, l31, wr, wc, acc);
    ACC_STORE(z, KK)
  }
}

// Launch C: j<512  -> out partials (split-K=8, 16 iters): outp[ks] = xb@Wt^T
//           j>=512 -> gu partials (split-K=16, 8 iters):  gup[ks] = g@Vb^T
__global__ __launch_bounds__(256, 3)
void cgo_k(const unsigned short* __restrict__ xb,   // (BB,KK)
           const unsigned short* __restrict__ Wt,   // (DD,KK)
           const unsigned short* __restrict__ g,    // (BB,KK)
           const unsigned short* __restrict__ Vb,   // (CC,KK)
           float* __restrict__ outp,                // 8 x (BB,DD)
           float* __restrict__ gup) {               // 16 x (BB,CC)
  __shared__ unsigned short As[3][4096];
  __shared__ unsigned short Bs[3][4096];
  LANE_SETUP
  const int j = blockIdx.x;
  f32x16 acc[2][2];
  ACC_INIT(acc)
  if (j < 512) {
    const int T = j >> 3, ks = j & 7;                // T in [0,64)
    const int bm = (T >> 4) * 128, bn = (T & 15) * 128;
    mm2(xb + (size_t)(bm + l) * KK + ks * 512,
        Wt + (size_t)(bn + l) * KK + ks * 512,
        KK, 16, &As[0][0], &Bs[0][0], w, hw, l31, wr, wc, acc);
    float* dst = outp + (size_t)ks * BB * DD;
    ACC_STORE(dst, DD)
  } else {
    const int jj = j - 512;                          // [0,256)
    const int T = jj >> 4, ks = jj & 15;             // T in [0,16)
    const int bm = (T >> 2) * 128, bn = (T & 3) * 128;
    mm2(g  + (size_t)(bm + l) * KK + ks * 256,
        Vb + (size_t)(bn + l) * KK + ks * 256,
        KK, 8, &As[0][0], &Bs[0][0], w, hw, l31, wr, wc, acc);
    float* dst = gup + (size_t)ks * BB * CC;
    ACC_STORE(dst, CC)
  }
}

// Launch B: prox-x over BB*KK: v = sum 4 gxp; x=prox(x-2lr*v, lr*g*causes(z));
// writes x, xb, g
__global__ __launch_bounds__(256) void ep_x_k(const float* __restrict__ gxp,
                                              const float* __restrict__ z,
                                              float* __restrict__ x,
                                              unsigned short* __restrict__ xb,
                                              unsigned short* __restrict__ g) {
  const int i = blockIdx.x * 256 + threadIdx.x;
  f32x4 v = f32x4{0.f, 0.f, 0.f, 0.f};
#pragma unroll
  for (int k = 0; k < 4; k++) v += ((const f32x4*)(gxp + (size_t)k * BB * KK))[i];
  const f32x4 zv = ((const f32x4*)z)[i];
  const f32x4 xo = ((const f32x4*)x)[i];
  f32x4 xn, gg;
#pragma unroll
  for (int j = 0; j < 4; j++) {
    const float e = __expf(-zv[j]);
    const float thr = (LR * GAMMA * 0.5f) * (1.0f + e);
    const float xv = xo[j] - (2.0f * LR) * v[j];
    const float t = fmaxf(xv - thr, 0.f) + fminf(xv + thr, 0.f);
    xn[j] = t;
    gg[j] = (-0.5f * GAMMA) * e * fabsf(t);
  }
  ((f32x4*)x)[i] = xn;
  store4bf(xb + (size_t)i * 4, xn);
  store4bf(g + (size_t)i * 4, gg);
}

// Launch D: j<256  -> u-update (sum 16 gup + prox -> u, ub)   [256 blocks]
//           j>=256 -> r = bf16(sum 8 outp - inputs)           [1024 blocks]
__global__ __launch_bounds__(256) void ud_k(const float* __restrict__ gup,
                                            const float* __restrict__ outp,
                                            const float* __restrict__ inputs,
                                            float* __restrict__ u,
                                            unsigned short* __restrict__ ub,
                                            unsigned short* __restrict__ r) {
  const int j = blockIdx.x;
  if (j < 256) {
    const int i = j * 256 + threadIdx.x;
    f32x4 v = f32x4{0.f, 0.f, 0.f, 0.f};
#pragma unroll
    for (int k = 0; k < 16; k++) v += ((const f32x4*)(gup + (size_t)k * BB * CC))[i];
    const f32x4 uo = ((const f32x4*)u)[i];
    f32x4 un;
#pragma unroll
    for (int jj = 0; jj < 4; jj++) {
      const float gv = v[jj] + (0.02f * GAMMA) * uo[jj];
      const float uu = uo[jj] - LR * gv;
      un[jj] = fmaxf(uu - (LR * GAMMA), 0.f) + fminf(uu + (LR * GAMMA), 0.f);
    }
    ((f32x4*)u)[i] = un;
    store4bf(ub + (size_t)i * 4, un);
  } else {
    const int i = (j - 256) * 256 + threadIdx.x;     // needs 1024 blocks
    f32x4 s = f32x4{0.f, 0.f, 0.f, 0.f};
#pragma unroll
    for (int k = 0; k < 8; k++) s += ((const f32x4*)(outp + (size_t)k * BB * DD))[i];
    s -= ((const f32x4*)inputs)[i];
    store4bf(r + (size_t)i * 4, s);
  }
}

// final: out = sum 8 outp (fp32)
__global__ __launch_bounds__(256) void ep_out_k(const float* __restrict__ outp,
                                                float* __restrict__ out) {
  const int i = blockIdx.x * 256 + threadIdx.x;
  f32x4 s = f32x4{0.f, 0.f, 0.f, 0.f};
#pragma unroll
  for (int k = 0; k < 8; k++) s += ((const f32x4*)(outp + (size_t)k * BB * DD))[i];
  ((f32x4*)out)[i] = s;
}

// ---- one-time conversion / init kernels ----

__global__ __launch_bounds__(256)
void convtrans_k(const float* __restrict__ src, unsigned short* __restrict__ b,
                 unsigned short* __restrict__ t, int R, int C) {
  __shared__ float tile[64][65];
  const int tid = threadIdx.x;
  const int tr = blockIdx.y * 64;
  const int tc = blockIdx.x * 64;
  const int lr = tid >> 4;
  const int lc = (tid & 15) * 4;
#pragma unroll
  for (int i = 0; i < 4; i++) {
    const float4 v = *(const float4*)(src + (size_t)(tr + lr + 16 * i) * C + tc + lc);
    tile[lr + 16 * i][lc + 0] = v.x;
    tile[lr + 16 * i][lc + 1] = v.y;
    tile[lr + 16 * i][lc + 2] = v.z;
    tile[lr + 16 * i][lc + 3] = v.w;
    store4bf(b + (size_t)(tr + lr + 16 * i) * C + tc + lc, f32x4{v.x, v.y, v.z, v.w});
  }
  __syncthreads();
#pragma unroll
  for (int j = 0; j < 16; j++) {
    const int idx = tid + j * 256;
    const int c = idx >> 6;
    const int r = idx & 63;
    t[(size_t)(tc + c) * R + tr + r] = f2bf(tile[r][c]);
  }
}

__global__ void zero_k(unsigned int* p, int n) {
  const int i = blockIdx.x * blockDim.x + threadIdx.x;
  if (i < n) p[i] = 0u;
}

__global__ void initu_k(const float* __restrict__ u0, float* __restrict__ u,
                        unsigned short* __restrict__ ub, int n) {
  const int i = blockIdx.x * blockDim.x + threadIdx.x;
  if (i < n) {
    const float v = u0[i];
    u[i] = v;
    ub[i] = f2bf(v);
  }
}

__global__ __launch_bounds__(256) void r0_k(const float* __restrict__ inputs,
                                            unsigned short* __restrict__ r) {
  const int i = blockIdx.x * 256 + threadIdx.x;
  const f32x4 v = ((const f32x4*)inputs)[i];
  store4bf(r + (size_t)i * 4, f32x4{0.f, 0.f, 0.f, 0.f} - v);
}

extern "C" void kernel_launch(void* const* d_in, const int* in_sizes, int n_in,
                              void* d_out, int out_size, void* d_ws, size_t ws_size,
                              hipStream_t stream) {
  const float* inputs = (const float*)d_in[0];   // (BB, DD)
  const float* W      = (const float*)d_in[1];   // (KK, DD)
  const float* V      = (const float*)d_in[2];   // (CC, KK)
  const float* u0     = (const float*)d_in[3];   // (BB, CC)
  float* out = (float*)d_out;                    // (BB, DD)

  char* ws = (char*)d_ws;
  size_t off = 0;
  auto alloc = [&](size_t bytes) -> void* {
    void* p = ws + off;
    off += (bytes + 255) & ~(size_t)255;
    return p;
  };
  unsigned short* Wb = (unsigned short*)alloc((size_t)KK * DD * 2);  // W  (KK,DD)
  unsigned short* Wt = (unsigned short*)alloc((size_t)DD * KK * 2);  // W^T (DD,KK)
  unsigned short* Vb = (unsigned short*)alloc((size_t)CC * KK * 2);  // V  (CC,KK)
  unsigned short* Vt = (unsigned short*)alloc((size_t)KK * CC * 2);  // V^T (KK,CC)
  unsigned short* xb = (unsigned short*)alloc((size_t)BB * KK * 2);
  unsigned short* g  = (unsigned short*)alloc((size_t)BB * KK * 2);
  unsigned short* r  = (unsigned short*)alloc((size_t)BB * DD * 2);
  unsigned short* ub = (unsigned short*)alloc((size_t)BB * CC * 2);
  float* x    = (float*)alloc((size_t)BB * KK * 4);
  float* z    = (float*)alloc((size_t)BB * KK * 4);
  float* u    = (float*)alloc((size_t)BB * CC * 4);
  float* gxp  = (float*)alloc((size_t)4 * BB * KK * 4);   // 32 MB
  float* outp = (float*)alloc((size_t)8 * BB * DD * 4);   // 32 MB
  float* gup  = (float*)alloc((size_t)16 * BB * CC * 4);  // 16 MB

  convtrans_k<<<dim3(DD / 64, KK / 64), 256, 0, stream>>>(W, Wb, Wt, KK, DD);
  convtrans_k<<<dim3(KK / 64, CC / 64), 256, 0, stream>>>(V, Vb, Vt, CC, KK);
  zero_k<<<(BB * KK / 2 + 255) / 256, 256, 0, stream>>>((unsigned int*)xb, BB * KK / 2);
  zero_k<<<(BB * KK + 255) / 256, 256, 0, stream>>>((unsigned int*)x, BB * KK);
  initu_k<<<(BB * CC + 255) / 256, 256, 0, stream>>>(u0, u, ub, BB * CC);
  r0_k<<<BB * DD / 4 / 256, 256, 0, stream>>>(inputs, r);

  for (int t = 0; t < 9; t++) {
    // A: gx-partials_t (512 x 16 iters) + z_t (128 x 16 iters)
    zgxp_k<<<640, 256, 0, stream>>>(r, Wb, ub, Vt, gxp, z);
    // B: prox-x -> x_{t+1}, xb, g_t
    ep_x_k<<<BB * KK / 4 / 256, 256, 0, stream>>>(gxp, z, x, xb, g);
    if (t < 8) {
      // C: out-partials_{t+1} (512 x 16) + gu-partials_t (256 x 8)
      cgo_k<<<768, 256, 0, stream>>>(xb, Wt, g, Vb, outp, gup);
      // D: u-prox_t (256 blocks) + r_{t+1} (1024 blocks)
      ud_k<<<1280, 256, 0, stream>>>(gup, outp, inputs, u, ub, r);
    } else {
      // C: out-partials_9 only
      cgo_k<<<512, 256, 0, stream>>>(xb, Wt, g, Vb, outp, gup);
      // D: final sum -> d_out
      ep_out_k<<<BB * DD / 4 / 256, 256, 0, stream>>>(outp, out);
    }
  }
}

// Round 10
// 585.481 us; speedup vs baseline: 1.2405x; 1.2405x over previous
//
#include <hip/hip_runtime.h>
#include <hip/hip_bf16.h>

#define BB 512      // batch
#define DD 2048     // input dim
#define KK 4096     // code dim
#define CC 512      // cause dim
#define LR 0.001f
#define GAMMA 0.1f

typedef __attribute__((ext_vector_type(8))) short short8;
typedef __attribute__((ext_vector_type(4))) float f32x4;

__device__ __forceinline__ unsigned short f2bf(float f) {
  union { float f; unsigned u; } x; x.f = f;
  unsigned r = x.u + 0x7FFF + ((x.u >> 16) & 1);   // RNE
  return (unsigned short)(r >> 16);
}

__device__ __forceinline__ void g2l16(const void* g, void* l) {
  __builtin_amdgcn_global_load_lds(
      (const __attribute__((address_space(1))) void*)g,
      (__attribute__((address_space(3))) void*)l, 16, 0, 0);
}

__device__ __forceinline__ void store4bf(unsigned short* p, f32x4 v) {
  const unsigned lo = (unsigned)f2bf(v[0]) | ((unsigned)f2bf(v[1]) << 16);
  const unsigned hi = (unsigned)f2bf(v[2]) | ((unsigned)f2bf(v[3]) << 16);
  *(uint2*)p = uint2{lo, hi};
}

// ---------------------------------------------------------------------------
// 64(M)x128(N)-tile K-loop, BK=64, mfma 16x16x32, 4 waves 2x2, wave tile
// 32x64 (acc 2x4 = 16 MFMA + 6 ds_read_b128 + 6 g2l16 per wave-iter ->
// 2x FLOP per LDS byte vs 64x64). R8's PROVEN staging: 8 lanes/row, XOR
// swizzle via pre-swizzled global source (16 lines/instr, no redundancy).
// 3 buffer sets (A 8KB + B 16KB = 72KB -> 2 blocks/CU), 2 tiles ahead,
// counted vmcnt(6). Single barrier/iter (R4-R8 proven race-free).
// ---------------------------------------------------------------------------
__device__ __forceinline__ void mm_t(
    const unsigned short* __restrict__ ag,   // lane-adjusted A base
    const unsigned short* __restrict__ bg,   // lane-adjusted B base
    int Kd, int nt,
    unsigned short* As,                      // [3][4096]
    unsigned short* Bs,                      // [3][8192]
    int lbase, int fr, int fq, int wr, int wc,
    f32x4 acc[2][4]) {
  auto STG = [&](int ti, int buf) {
    const int k0 = ti << 6;
    unsigned short* Ab = As + buf * 4096;
    unsigned short* Bb = Bs + buf * 8192;
    g2l16(ag + k0, Ab + lbase);
    g2l16(ag + (size_t)32 * Kd + k0, Ab + 2048 + lbase);
    g2l16(bg + k0, Bb + lbase);
    g2l16(bg + (size_t)32 * Kd + k0, Bb + 2048 + lbase);
    g2l16(bg + (size_t)64 * Kd + k0, Bb + 4096 + lbase);
    g2l16(bg + (size_t)96 * Kd + k0, Bb + 6144 + lbase);
  };
  STG(0, 0);
  if (nt > 1) STG(1, 1);
  int cb = 0, sb = 2;
  for (int t = 0; t < nt; t++) {
    if (t + 1 < nt) asm volatile("s_waitcnt vmcnt(6)" ::: "memory");
    else            asm volatile("s_waitcnt vmcnt(0)" ::: "memory");
    __builtin_amdgcn_s_barrier();
    if (t + 2 < nt) STG(t + 2, sb);

    const unsigned short* Ab = As + cb * 4096;
    const unsigned short* Bb = Bs + cb * 8192;
#pragma unroll
    for (int kk = 0; kk < 2; kk++) {
      const int kx = (kk * 64 + fq * 16) ^ ((fr & 7) << 4);
      short8 af[2], bf2[4];
#pragma unroll
      for (int m = 0; m < 2; m++)
        af[m] = *(const short8*)((const char*)Ab + (wr * 32 + m * 16 + fr) * 128 + kx);
#pragma unroll
      for (int n = 0; n < 4; n++)
        bf2[n] = *(const short8*)((const char*)Bb + (wc * 64 + n * 16 + fr) * 128 + kx);
#pragma unroll
      for (int m = 0; m < 2; m++)
#pragma unroll
        for (int n = 0; n < 4; n++)
          acc[m][n] = __builtin_amdgcn_mfma_f32_16x16x32_bf16(af[m], bf2[n], acc[m][n], 0, 0, 0);
    }
    cb = (cb + 1 == 3) ? 0 : cb + 1;
    sb = (sb + 1 == 3) ? 0 : sb + 1;
  }
}

#define LANE_SETUP                                             \
  const int tid = threadIdx.x;                                 \
  const int w = tid >> 6, l = tid & 63;                        \
  const int wr = w >> 1, wc = w & 1;                           \
  const int fr = l & 15, fq = l >> 4;                          \
  const int srow = w * 8 + (l >> 3);                           \
  const int scol = 8 * ((l & 7) ^ (l >> 3));                   \
  const int lbase = w * 512;

#define ACC_INIT(a)                                            \
  _Pragma("unroll") for (int m = 0; m < 2; m++)                \
  _Pragma("unroll") for (int n = 0; n < 4; n++)                \
      a[m][n] = f32x4{0.f, 0.f, 0.f, 0.f};

// C/D 16x16 layout: col = lane&15, row = (lane>>4)*4 + j
#define ACC_STORE(dst, N)                                      \
  _Pragma("unroll") for (int m = 0; m < 2; m++)                \
  _Pragma("unroll") for (int n = 0; n < 4; n++)                \
  _Pragma("unroll") for (int j2 = 0; j2 < 4; j2++)             \
      (dst)[(size_t)(bm + wr * 32 + m * 16 + fq * 4 + j2) * (N)\
            + bn + wc * 64 + n * 16 + fr] = acc[m][n][j2];

// Launch A: j<1024 -> gx partials (split-K=4, 8 iters): gxp[ks] = r@Wb^T
//           j>=1024 -> z tiles (8 iters): z = ub@Vt^T
__global__ __launch_bounds__(256, 2)
void zgxp_k(const unsigned short* __restrict__ r,    // (BB,DD)
            const unsigned short* __restrict__ Wb,   // (KK,DD)
            const unsigned short* __restrict__ ub,   // (BB,CC)
            const unsigned short* __restrict__ Vt,   // (KK,CC)
            float* __restrict__ gxp,                 // 4 x (BB,KK)
            float* __restrict__ z) {                 // (BB,KK)
  __shared__ unsigned short As[3][4096];
  __shared__ unsigned short Bs[3][8192];
  LANE_SETUP
  const int j = blockIdx.x;
  f32x4 acc[2][4];
  ACC_INIT(acc)
  if (j < 1024) {
    const int T = j >> 2, ks = j & 3;                // T in [0,256)
    const int bm = (T >> 5) * 64, bn = (T & 31) * 128;
    mm_t(r  + (size_t)(bm + srow) * DD + ks * 512 + scol,
         Wb + (size_t)(bn + srow) * DD + ks * 512 + scol,
         DD, 8, &As[0][0], &Bs[0][0], lbase, fr, fq, wr, wc, acc);
    float* dst = gxp + (size_t)ks * BB * KK;
    ACC_STORE(dst, KK)
  } else {
    const int T = j - 1024;                          // [0,256)
    const int bm = (T >> 5) * 64, bn = (T & 31) * 128;
    mm_t(ub + (size_t)(bm + srow) * CC + scol,
         Vt + (size_t)(bn + srow) * CC + scol,
         CC, 8, &As[0][0], &Bs[0][0], lbase, fr, fq, wr, wc, acc);
    ACC_STORE(z, KK)
  }
}

// Launch C: j<1024 -> out partials (split-K=8, 8 iters): outp[ks] = xb@Wt^T
//           j>=1024 -> gu partials (split-K=8, 8 iters): gup[ks] = g@Vb^T
__global__ __launch_bounds__(256, 2)
void cgo_k(const unsigned short* __restrict__ xb,   // (BB,KK)
           const unsigned short* __restrict__ Wt,   // (DD,KK)
           const unsigned short* __restrict__ g,    // (BB,KK)
           const unsigned short* __restrict__ Vb,   // (CC,KK)
           float* __restrict__ outp,                // 8 x (BB,DD)
           float* __restrict__ gup) {               // 8 x (BB,CC)
  __shared__ unsigned short As[3][4096];
  __shared__ unsigned short Bs[3][8192];
  LANE_SETUP
  const int j = blockIdx.x;
  f32x4 acc[2][4];
  ACC_INIT(acc)
  if (j < 1024) {
    const int T = j >> 3, ks = j & 7;                // T in [0,128)
    const int bm = (T >> 4) * 64, bn = (T & 15) * 128;
    mm_t(xb + (size_t)(bm + srow) * KK + ks * 512 + scol,
         Wt + (size_t)(bn + srow) * KK + ks * 512 + scol,
         KK, 8, &As[0][0], &Bs[0][0], lbase, fr, fq, wr, wc, acc);
    float* dst = outp + (size_t)ks * BB * DD;
    ACC_STORE(dst, DD)
  } else {
    const int jj = j - 1024;                         // [0,256)
    const int T = jj >> 3, ks = jj & 7;              // T in [0,32)
    const int bm = (T >> 2) * 64, bn = (T & 3) * 128;
    mm_t(g  + (size_t)(bm + srow) * KK + ks * 512 + scol,
         Vb + (size_t)(bn + srow) * KK + ks * 512 + scol,
         KK, 8, &As[0][0], &Bs[0][0], lbase, fr, fq, wr, wc, acc);
    float* dst = gup + (size_t)ks * BB * CC;
    ACC_STORE(dst, CC)
  }
}

// Launch B: prox-x over BB*KK: v = sum 4 gxp; x=prox(x-2lr*v, lr*g*causes(z));
// writes x, xb, g
__global__ __launch_bounds__(256) void ep_x_k(const float* __restrict__ gxp,
                                              const float* __restrict__ z,
                                              float* __restrict__ x,
                                              unsigned short* __restrict__ xb,
                                              unsigned short* __restrict__ g) {
  const int i = blockIdx.x * 256 + threadIdx.x;
  f32x4 v = f32x4{0.f, 0.f, 0.f, 0.f};
#pragma unroll
  for (int k = 0; k < 4; k++) v += ((const f32x4*)(gxp + (size_t)k * BB * KK))[i];
  const f32x4 zv = ((const f32x4*)z)[i];
  const f32x4 xo = ((const f32x4*)x)[i];
  f32x4 xn, gg;
#pragma unroll
  for (int j = 0; j < 4; j++) {
    const float e = __expf(-zv[j]);
    const float thr = (LR * GAMMA * 0.5f) * (1.0f + e);
    const float xv = xo[j] - (2.0f * LR) * v[j];
    const float t = fmaxf(xv - thr, 0.f) + fminf(xv + thr, 0.f);
    xn[j] = t;
    gg[j] = (-0.5f * GAMMA) * e * fabsf(t);
  }
  ((f32x4*)x)[i] = xn;
  store4bf(xb + (size_t)i * 4, xn);
  store4bf(g + (size_t)i * 4, gg);
}

// Launch D: j<256  -> u-update (sum 8 gup + prox -> u, ub)   [256 blocks]
//           j>=256 -> r = bf16(sum 8 outp - inputs)          [1024 blocks]
__global__ __launch_bounds__(256) void ud_k(const float* __restrict__ gup,
                                            const float* __restrict__ outp,
                                            const float* __restrict__ inputs,
                                            float* __restrict__ u,
                                            unsigned short* __restrict__ ub,
                                            unsigned short* __restrict__ r) {
  const int j = blockIdx.x;
  if (j < 256) {
    const int i = j * 256 + threadIdx.x;
    f32x4 v = f32x4{0.f, 0.f, 0.f, 0.f};
#pragma unroll
    for (int k = 0; k < 8; k++) v += ((const f32x4*)(gup + (size_t)k * BB * CC))[i];
    const f32x4 uo = ((const f32x4*)u)[i];
    f32x4 un;
#pragma unroll
    for (int jj = 0; jj < 4; jj++) {
      const float gv = v[jj] + (0.02f * GAMMA) * uo[jj];
      const float uu = uo[jj] - LR * gv;
      un[jj] = fmaxf(uu - (LR * GAMMA), 0.f) + fminf(uu + (LR * GAMMA), 0.f);
    }
    ((f32x4*)u)[i] = un;
    store4bf(ub + (size_t)i * 4, un);
  } else {
    const int i = (j - 256) * 256 + threadIdx.x;     // 1024 blocks
    f32x4 s = f32x4{0.f, 0.f, 0.f, 0.f};
#pragma unroll
    for (int k = 0; k < 8; k++) s += ((const f32x4*)(outp + (size_t)k * BB * DD))[i];
    s -= ((const f32x4*)inputs)[i];
    store4bf(r + (size_t)i * 4, s);
  }
}

// final: out = sum 8 outp (fp32)
__global__ __launch_bounds__(256) void ep_out_k(const float* __restrict__ outp,
                                                float* __restrict__ out) {
  const int i = blockIdx.x * 256 + threadIdx.x;
  f32x4 s = f32x4{0.f, 0.f, 0.f, 0.f};
#pragma unroll
  for (int k = 0; k < 8; k++) s += ((const f32x4*)(outp + (size_t)k * BB * DD))[i];
  ((f32x4*)out)[i] = s;
}

// ---- one-time conversion / init kernels ----

__global__ __launch_bounds__(256)
void convtrans_k(const float* __restrict__ src, unsigned short* __restrict__ b,
                 unsigned short* __restrict__ t, int R, int C) {
  __shared__ float tile[64][65];
  const int tid = threadIdx.x;
  const int tr = blockIdx.y * 64;
  const int tc = blockIdx.x * 64;
  const int lr = tid >> 4;
  const int lc = (tid & 15) * 4;
#pragma unroll
  for (int i = 0; i < 4; i++) {
    const float4 v = *(const float4*)(src + (size_t)(tr + lr + 16 * i) * C + tc + lc);
    tile[lr + 16 * i][lc + 0] = v.x;
    tile[lr + 16 * i][lc + 1] = v.y;
    tile[lr + 16 * i][lc + 2] = v.z;
    tile[lr + 16 * i][lc + 3] = v.w;
    store4bf(b + (size_t)(tr + lr + 16 * i) * C + tc + lc, f32x4{v.x, v.y, v.z, v.w});
  }
  __syncthreads();
#pragma unroll
  for (int j = 0; j < 16; j++) {
    const int idx = tid + j * 256;
    const int c = idx >> 6;
    const int r = idx & 63;
    t[(size_t)(tc + c) * R + tr + r] = f2bf(tile[r][c]);
  }
}

__global__ void zero_k(unsigned int* p, int n) {
  const int i = blockIdx.x * blockDim.x + threadIdx.x;
  if (i < n) p[i] = 0u;
}

__global__ void initu_k(const float* __restrict__ u0, float* __restrict__ u,
                        unsigned short* __restrict__ ub, int n) {
  const int i = blockIdx.x * blockDim.x + threadIdx.x;
  if (i < n) {
    const float v = u0[i];
    u[i] = v;
    ub[i] = f2bf(v);
  }
}

__global__ __launch_bounds__(256) void r0_k(const float* __restrict__ inputs,
                                            unsigned short* __restrict__ r) {
  const int i = blockIdx.x * 256 + threadIdx.x;
  const f32x4 v = ((const f32x4*)inputs)[i];
  store4bf(r + (size_t)i * 4, f32x4{0.f, 0.f, 0.f, 0.f} - v);
}

extern "C" void kernel_launch(void* const* d_in, const int* in_sizes, int n_in,
                              void* d_out, int out_size, void* d_ws, size_t ws_size,
                              hipStream_t stream) {
  const float* inputs = (const float*)d_in[0];   // (BB, DD)
  const float* W      = (const float*)d_in[1];   // (KK, DD)
  const float* V      = (const float*)d_in[2];   // (CC, KK)
  const float* u0     = (const float*)d_in[3];   // (BB, CC)
  float* out = (float*)d_out;                    // (BB, DD)

  char* ws = (char*)d_ws;
  size_t off = 0;
  auto alloc = [&](size_t bytes) -> void* {
    void* p = ws + off;
    off += (bytes + 255) & ~(size_t)255;
    return p;
  };
  unsigned short* Wb = (unsigned short*)alloc((size_t)KK * DD * 2);  // W  (KK,DD)
  unsigned short* Wt = (unsigned short*)alloc((size_t)DD * KK * 2);  // W^T (DD,KK)
  unsigned short* Vb = (unsigned short*)alloc((size_t)CC * KK * 2);  // V  (CC,KK)
  unsigned short* Vt = (unsigned short*)alloc((size_t)KK * CC * 2);  // V^T (KK,CC)
  unsigned short* xb = (unsigned short*)alloc((size_t)BB * KK * 2);
  unsigned short* g  = (unsigned short*)alloc((size_t)BB * KK * 2);
  unsigned short* r  = (unsigned short*)alloc((size_t)BB * DD * 2);
  unsigned short* ub = (unsigned short*)alloc((size_t)BB * CC * 2);
  float* x    = (float*)alloc((size_t)BB * KK * 4);
  float* z    = (float*)alloc((size_t)BB * KK * 4);
  float* u    = (float*)alloc((size_t)BB * CC * 4);
  float* gxp  = (float*)alloc((size_t)4 * BB * KK * 4);   // 32 MB
  float* outp = (float*)alloc((size_t)8 * BB * DD * 4);   // 32 MB
  float* gup  = (float*)alloc((size_t)8 * BB * CC * 4);   // 8 MB

  convtrans_k<<<dim3(DD / 64, KK / 64), 256, 0, stream>>>(W, Wb, Wt, KK, DD);
  convtrans_k<<<dim3(KK / 64, CC / 64), 256, 0, stream>>>(V, Vb, Vt, CC, KK);
  zero_k<<<(BB * KK / 2 + 255) / 256, 256, 0, stream>>>((unsigned int*)xb, BB * KK / 2);
  zero_k<<<(BB * KK + 255) / 256, 256, 0, stream>>>((unsigned int*)x, BB * KK);
  initu_k<<<(BB * CC + 255) / 256, 256, 0, stream>>>(u0, u, ub, BB * CC);
  r0_k<<<BB * DD / 4 / 256, 256, 0, stream>>>(inputs, r);

  for (int t = 0; t < 9; t++) {
    // A: gx-partials_t (1024 x 8 iters) + z_t (256 x 8 iters)
    zgxp_k<<<1280, 256, 0, stream>>>(r, Wb, ub, Vt, gxp, z);
    // B: prox-x -> x_{t+1}, xb, g_t
    ep_x_k<<<BB * KK / 4 / 256, 256, 0, stream>>>(gxp, z, x, xb, g);
    if (t < 8) {
      // C: out-partials_{t+1} (1024 x 8) + gu-partials_t (256 x 8)
      cgo_k<<<1280, 256, 0, stream>>>(xb, Wt, g, Vb, outp, gup);
      // D: u-prox_t (256 blocks) + r_{t+1} (1024 blocks)
      ud_k<<<1280, 256, 0, stream>>>(gup, outp, inputs, u, ub, r);
    } else {
      // C: out-partials_9 only
      cgo_k<<<1024, 256, 0, stream>>>(xb, Wt, g, Vb, outp, gup);
      // D: final sum -> d_out
      ep_out_k<<<BB * DD / 4 / 256, 256, 0, stream>>>(outp, out);
    }
  }
}